// Round 8
// baseline (280.914 us; speedup 1.0000x reference)
//
#include <hip/hip_runtime.h>

typedef __bf16 bf16;
typedef bf16 bf16x8 __attribute__((ext_vector_type(8)));
typedef float floatx16 __attribute__((ext_vector_type(16)));

#define AS1 __attribute__((address_space(1)))
#define AS3 __attribute__((address_space(3)))

#define KTOT 26112   // A2/B2 leading dim: 48*512 spectral + 3*512 AR columns

// ---------------------------------------------------------------------------
// Round-2-verified machinery for conv: 128x64 staging + 2x2 32x32x16 MFMA.
// ---------------------------------------------------------------------------
__device__ __forceinline__ void stage_tile(const bf16* g, int ld, bf16* lds, int tid) {
#pragma unroll
    for (int it = 0; it < 4; ++it) {
        int q    = it * 256 + tid;        // 0..1023, 8 bf16 per q
        int row  = q >> 3;
        int col8 = (q & 7) ^ (row & 7);   // swizzle on global side
        __builtin_amdgcn_global_load_lds(
            (const AS1 void*)(g + (size_t)row * ld + col8 * 8),
            (AS3 void*)(lds + q * 8), 16, 0, 0);
    }
}

__device__ __forceinline__ void mfma_block(const bf16* lA, const bf16* lB,
                                           floatx16 acc[2][2], int lane, int wm, int wn) {
    const int lrow = lane & 31;
    const int lk   = lane >> 5;
#pragma unroll
    for (int s = 0; s < 4; ++s) {   // four K=16 steps per BK=64
        bf16x8 af[2], bfr[2];
        const int c8 = s * 2 + lk;
#pragma unroll
        for (int mi = 0; mi < 2; ++mi) {
            int r = wm * 64 + mi * 32 + lrow;
            af[mi] = *(const bf16x8*)(lA + r * 64 + ((c8 ^ (r & 7)) << 3));
        }
#pragma unroll
        for (int ni = 0; ni < 2; ++ni) {
            int r = wn * 64 + ni * 32 + lrow;
            bfr[ni] = *(const bf16x8*)(lB + r * 64 + ((c8 ^ (r & 7)) << 3));
        }
#pragma unroll
        for (int mi = 0; mi < 2; ++mi)
#pragma unroll
            for (int ni = 0; ni < 2; ++ni)
                acc[mi][ni] = __builtin_amdgcn_mfma_f32_32x32x16_bf16(
                    af[mi], bfr[ni], acc[mi][ni], 0, 0, 0);
    }
}

// C/D mapping for 32x32 (m74/m101): col=lane&31, row=(r&3)+8*(r>>2)+4*(lane>>5)
#define CD_ROW(r, lane) (((r) & 3) + 8 * ((r) >> 2) + 4 * ((lane) >> 5))

// ---------------------------------------------------------------------------
// Conv phase, even/odd-decomposed (round-2 verified, byte-identical).
// ---------------------------------------------------------------------------
__global__ __launch_bounds__(256) void conv_gemm(const bf16* __restrict__ Tb,
                                                 const bf16* __restrict__ xT2,
                                                 bf16* __restrict__ A2) {
    __shared__ bf16 lA[128 * 64], lB[128 * 64];
    const int tid = threadIdx.x;
    const int lane = tid & 63, wave = tid >> 6, wm = wave & 1, wn = wave >> 1;
    const int bid = blockIdx.x;
    const int a    = 7 - (bid / 384);      // longest-first (LPT)
    const int rem  = bid % 384;
    const int dblk = rem / 48;             // 0..7 over d' = p*512 + d
    const int kw   = rem % 48;             // k*2 + w

    floatx16 acc[2][2];
#pragma unroll
    for (int mi = 0; mi < 2; ++mi)
#pragma unroll
        for (int ni = 0; ni < 2; ++ni)
#pragma unroll
            for (int e = 0; e < 16; ++e) acc[mi][ni][e] = 0.f;

    for (int c = 0; c <= a; ++c) {
        const bf16* Ab = Tb + ((size_t)kw * 8 + (a - c)) * 16384;
        const bf16* Bb = xT2 + (size_t)(dblk * 128) * 1024 + c * 128;
#pragma unroll
        for (int kk = 0; kk < 128; kk += 64) {
            stage_tile(Ab + kk, 128, lA, tid);
            stage_tile(Bb + kk, 1024, lB, tid);
            __syncthreads();
            mfma_block(lA, lB, acc, lane, wm, wn);
            __syncthreads();
        }
    }
    const int w = kw & 1, k = kw >> 1;
    const int kv = w ? (24 + k) : k;
    const int p = dblk >> 2, dbase = (dblk & 3) * 128;
    bf16* Ocol = A2 + (size_t)kv * 512 + dbase;
#pragma unroll
    for (int mi = 0; mi < 2; ++mi)
#pragma unroll
        for (int ni = 0; ni < 2; ++ni)
#pragma unroll
            for (int r = 0; r < 16; ++r) {
                int tau = a * 128 + wm * 64 + mi * 32 + CD_ROW(r, lane);
                int t = 2 * tau + p + w;   // w=0: 2tau+p ; w=1: 2tau+1+p
                if (t < 2048) {
                    int col = wn * 64 + ni * 32 + (lane & 31);
                    Ocol[(size_t)t * KTOT + col] = (bf16)acc[mi][ni][r];
                }
            }
}

// ---------------------------------------------------------------------------
// Phase-interleaved projection GEMM (T3+T4+T5 on 32x32x16 machinery):
// BM=256 x BN=256 x BK=32; 512 thr = 8 waves (2M x 4N), wave C = 128x64
// = acc[4][2] of 32x32. Grid (8,2,16): sp in z splits K into 16 x 51 tiles
// -> 256 blocks = exactly 1/CU (96 KB LDS triple buffer).
// Per phase t (one BK=32 tile):
//   stage tile t+2 -> buf[(t+2)%3]   (4 gload_lds; buffer freed at phase t-1)
//   vmcnt(8)  : tiles t+1,t+2 (8 instrs) may stay in flight; t landed
//   s_barrier : all waves' loads for t landed -> publish
//   12x ds_read_b128 (A 8, B 4; each frag once); lgkmcnt(0)
//   setprio(1); 16x MFMA; setprio(0); s_barrier (reads retired -> next stage)
// Never drains vmcnt to 0 until the last two tiles (vmcnt(4)/vmcnt(0)).
// Epilogue: atomicAdd into out (zeroed by prep) -- no P2, no reduce kernel.
// BK=32 swizzle: col8 ^= (row>>1)&3 (4-slot domain), conflict-minimal.
// ---------------------------------------------------------------------------
__device__ __forceinline__ void stage32(const bf16* g, int ld, bf16* lds, int tid) {
#pragma unroll
    for (int it = 0; it < 2; ++it) {
        int q    = it * 512 + tid;        // 0..1023 over 256 rows x 4 slots
        int row  = q >> 2;
        int col8 = (q & 3) ^ ((row >> 1) & 3);
        __builtin_amdgcn_global_load_lds(
            (const AS1 void*)(g + (size_t)row * ld + col8 * 8),
            (AS3 void*)(lds + q * 8), 16, 0, 0);
    }
}

__global__ __launch_bounds__(512, 2) void proj_gemm(const bf16* __restrict__ A2,
                                                    const bf16* __restrict__ B2,
                                                    float* __restrict__ out) {
    __shared__ bf16 lA[3][256 * 32], lB[3][256 * 32];   // 96 KB
    const int tid = threadIdx.x;
    const int lane = tid & 63, w = tid >> 6;
    const int wm = w >> 2, wn = w & 3;          // 2M x 4N
    const int lrow = lane & 31, lk = lane >> 5;
    const int bm = blockIdx.x, bn = blockIdx.y, sp = blockIdx.z;
    const bf16* Ab = A2 + (size_t)bm * 256 * KTOT + sp * 1632;
    const bf16* Bb = B2 + (size_t)bn * 256 * KTOT + sp * 1632;

    floatx16 acc[4][2];
#pragma unroll
    for (int mi = 0; mi < 4; ++mi)
#pragma unroll
        for (int ni = 0; ni < 2; ++ni)
#pragma unroll
            for (int e = 0; e < 16; ++e) acc[mi][ni][e] = 0.f;

    // prologue: tiles 0,1 in flight (8 instrs/thread)
    stage32(Ab,      KTOT, lA[0], tid);
    stage32(Bb,      KTOT, lB[0], tid);
    stage32(Ab + 32, KTOT, lA[1], tid);
    stage32(Bb + 32, KTOT, lB[1], tid);

    for (int t = 0; t < 51; ++t) {
        const int b = t % 3;
        if (t + 2 < 51) {
            stage32(Ab + (size_t)(t + 2) * 32, KTOT, lA[(t + 2) % 3], tid);
            stage32(Bb + (size_t)(t + 2) * 32, KTOT, lB[(t + 2) % 3], tid);
        }
        if (t < 49) {
            asm volatile("s_waitcnt vmcnt(8)" ::: "memory");
        } else if (t == 49) {
            asm volatile("s_waitcnt vmcnt(4)" ::: "memory");
        } else {
            asm volatile("s_waitcnt vmcnt(0)" ::: "memory");
        }
        __builtin_amdgcn_sched_barrier(0);
        __builtin_amdgcn_s_barrier();            // tile t published block-wide
        __builtin_amdgcn_sched_barrier(0);

        const bf16* LA = lA[b];
        const bf16* LB = lB[b];
        bf16x8 af[4][2], bfr[2][2];
#pragma unroll
        for (int s = 0; s < 2; ++s) {
            const int c8 = s * 2 + lk;
#pragma unroll
            for (int mi = 0; mi < 4; ++mi) {
                int r = wm * 128 + mi * 32 + lrow;
                af[mi][s] = *(const bf16x8*)(LA + r * 32 + ((c8 ^ ((r >> 1) & 3)) << 3));
            }
#pragma unroll
            for (int ni = 0; ni < 2; ++ni) {
                int r = wn * 64 + ni * 32 + lrow;
                bfr[ni][s] = *(const bf16x8*)(LB + r * 32 + ((c8 ^ ((r >> 1) & 3)) << 3));
            }
        }
        asm volatile("s_waitcnt lgkmcnt(0)" ::: "memory");
        __builtin_amdgcn_sched_barrier(0);
        __builtin_amdgcn_s_setprio(1);
#pragma unroll
        for (int s = 0; s < 2; ++s)
#pragma unroll
            for (int mi = 0; mi < 4; ++mi)
#pragma unroll
                for (int ni = 0; ni < 2; ++ni)
                    acc[mi][ni] = __builtin_amdgcn_mfma_f32_32x32x16_bf16(
                        af[mi][s], bfr[ni][s], acc[mi][ni], 0, 0, 0);
        __builtin_amdgcn_s_setprio(0);
        __builtin_amdgcn_sched_barrier(0);
        __builtin_amdgcn_s_barrier();            // reads retired: buf reusable
        __builtin_amdgcn_sched_barrier(0);
    }

#pragma unroll
    for (int mi = 0; mi < 4; ++mi)
#pragma unroll
        for (int ni = 0; ni < 2; ++ni)
#pragma unroll
            for (int r = 0; r < 16; ++r) {
                int trow = bm * 256 + wm * 128 + mi * 32 + CD_ROW(r, lane);
                int o    = bn * 256 + wn * 64 + ni * 32 + (lane & 31);
                atomicAdd(out + (size_t)trow * 512 + o, acc[mi][ni][r]);
            }
}

// ---------------------------------------------------------------------------
// Fused prep (round-2 verified) + out-zeroing (round-4 verified):
//  [0,256)      xT2 parity-split transpose
//  [256,1792)   A2 AR columns (float4 loads)
//  [1792,3328)  B2 spectral: (Mp+Mm) -> kv=k, (Mp-Mm) -> kv=24+k, one pass
//  [3328,3840)  B2 AR columns
//  [3840,4224)  Tb E/O Toeplitz kernels
//  [4224,4230)  zero A2 row t=0, K-cols [12288,24576)
//  [4230,4742)  zero out (2048x512 f32) for proj's atomics
// ---------------------------------------------------------------------------
__global__ void prep_all(const float* __restrict__ x, const float* __restrict__ phi,
                         const float* __restrict__ M, const float* __restrict__ Mp,
                         const float* __restrict__ Mm, bf16* __restrict__ xT2,
                         bf16* __restrict__ A2, bf16* __restrict__ B2,
                         bf16* __restrict__ Tb, float* __restrict__ out) {
    __shared__ float smem[2][64 * 65];
    const int b = blockIdx.x, tid = threadIdx.x;
    if (b < 256) {
        // xT2: 64x64 LDS transpose tiles over (sigma, d')
        int dpt = (b >> 4) * 64, st = (b & 15) * 64;
        int p = dpt >> 9, dbase = dpt & 511;
#pragma unroll
        for (int it = 0; it < 16; ++it) {
            int q = it * 256 + tid;
            int r = q >> 6, cc = q & 63;   // r = sigma-local, cc = d-local
            smem[0][r * 65 + cc] = x[(size_t)(2 * (st + r) + p) * 512 + dbase + cc];
        }
        __syncthreads();
#pragma unroll
        for (int it = 0; it < 2; ++it) {
            int q = it * 256 + tid;
            int r = q >> 3, c8 = q & 7;    // r = d'-local, c8 = sigma-local/8
            bf16x8 v;
#pragma unroll
            for (int jj = 0; jj < 8; ++jj)
                v[jj] = (bf16)smem[0][(c8 * 8 + jj) * 65 + r];
            *(bf16x8*)&xT2[(size_t)(dpt + r) * 1024 + st + c8 * 8] = v;
        }
    } else if (b < 1792) {
        // A2 AR columns: A2[t][24576 + i*512 + d] = x[t-i][d]
        int idx8 = (b - 256) * 256 + tid;   // over 2048*192
        int t = idx8 / 192, q = idx8 % 192;
        int i = q >> 6, d8 = (q & 63) * 8;
        bf16x8 v;
        if (t - i >= 0) {
            const float* xp = x + (size_t)(t - i) * 512 + d8;
            float4 f0 = *(const float4*)(xp);
            float4 f1 = *(const float4*)(xp + 4);
            v[0] = (bf16)f0.x; v[1] = (bf16)f0.y; v[2] = (bf16)f0.z; v[3] = (bf16)f0.w;
            v[4] = (bf16)f1.x; v[5] = (bf16)f1.y; v[6] = (bf16)f1.z; v[7] = (bf16)f1.w;
        } else {
#pragma unroll
            for (int jj = 0; jj < 8; ++jj) v[jj] = (bf16)0.f;
        }
        *(bf16x8*)(A2 + (size_t)t * KTOT + 24576 + i * 512 + d8) = v;
    } else if (b < 3328) {
        // B2[o][k*512+d] = (Mp+Mm)[k][d][o];  B2[o][(24+k)*512+d] = (Mp-Mm)[k][d][o]
        int b2 = b - 1792;
        int k = b2 >> 6, rem2 = b2 & 63;
        int dt = (rem2 >> 3) * 64, ot = (rem2 & 7) * 64;
        const float* Sp = Mp + (size_t)k * 262144;
        const float* Sm = Mm + (size_t)k * 262144;
#pragma unroll
        for (int it = 0; it < 16; ++it) {
            int q = it * 256 + tid;
            int r = q >> 6, cc = q & 63;   // r = d-local, cc = o-local
            smem[0][r * 65 + cc] = Sp[(size_t)(dt + r) * 512 + ot + cc];
            smem[1][r * 65 + cc] = Sm[(size_t)(dt + r) * 512 + ot + cc];
        }
        __syncthreads();
#pragma unroll
        for (int it = 0; it < 2; ++it) {
            int q = it * 256 + tid;
            int r = q >> 3, c8 = q & 7;    // r = o-local, c8 = d-local/8
            bf16x8 vs, vd;
#pragma unroll
            for (int jj = 0; jj < 8; ++jj) {
                float av = smem[0][(c8 * 8 + jj) * 65 + r];
                float bv = smem[1][(c8 * 8 + jj) * 65 + r];
                vs[jj] = (bf16)(av + bv);
                vd[jj] = (bf16)(av - bv);
            }
            *(bf16x8*)&B2[(size_t)(ot + r) * KTOT + k * 512 + dt + c8 * 8] = vs;
            *(bf16x8*)&B2[(size_t)(ot + r) * KTOT + (24 + k) * 512 + dt + c8 * 8] = vd;
        }
    } else if (b < 3840) {
        // B2 AR columns: B2[o][24576 + i*512 + d] = M[o][d][i]
        int o = b - 3328;
        for (int q = tid; q < 1536; q += 256) smem[0][q] = M[(size_t)o * 1536 + q];
        __syncthreads();
        if (tid < 192) {
            int q = tid * 8;
            int i = q >> 9, d0 = q & 511;
            bf16x8 v;
#pragma unroll
            for (int jj = 0; jj < 8; ++jj) v[jj] = (bf16)smem[0][(d0 + jj) * 3 + i];
            *(bf16x8*)&B2[(size_t)o * KTOT + 24576 + q] = v;
        }
    } else if (b < 4224) {
        // Tb fill, one block per (kw,m): kernel phi_even (w=0) or phi_odd (w=1)
        int b3 = b - 3840;              // 0..383
        int kw = b3 >> 3, m = b3 & 7;
        int k = kw >> 1, w = kw & 1;
        if (tid < 255) {
            int sh = m * 128 - 127 + tid;
            smem[0][tid] = (sh >= 0) ? phi[(size_t)(2 * sh + w) * 24 + k] : 0.f;
        }
        __syncthreads();
        bf16* Tp = Tb + (size_t)b3 * 16384;
#pragma unroll
        for (int it = 0; it < 8; ++it) {
            int q = it * 256 + tid;     // over 128 i x 16 j8
            int i = q >> 4, j8 = (q & 15) * 8;
            bf16x8 v;
#pragma unroll
            for (int jj = 0; jj < 8; ++jj)
                v[jj] = (bf16)smem[0][127 + i - (j8 + jj)];
            *(bf16x8*)(Tp + i * 128 + j8) = v;
        }
    } else if (b < 4230) {
        // zero A2[0][12288..24576): O-part has no contribution at t=0
        int off = 12288 + (b - 4224) * 2048 + tid * 8;
        bf16x8 z;
#pragma unroll
        for (int jj = 0; jj < 8; ++jj) z[jj] = (bf16)0.f;
        *(bf16x8*)(A2 + off) = z;
    } else {
        // zero out: 2048*512 f32
        int idx = ((b - 4230) * 256 + tid) * 8;
        float4 z4 = make_float4(0.f, 0.f, 0.f, 0.f);
        *(float4*)(out + idx)     = z4;
        *(float4*)(out + idx + 4) = z4;
    }
}

// ---------------------------------------------------------------------------
// Launch
// ---------------------------------------------------------------------------
extern "C" void kernel_launch(void* const* d_in, const int* in_sizes, int n_in,
                              void* d_out, int out_size, void* d_ws, size_t ws_size,
                              hipStream_t stream) {
    const float* x   = (const float*)d_in[0];
    const float* phi = (const float*)d_in[1];
    const float* M   = (const float*)d_in[2];
    const float* Mp  = (const float*)d_in[3];
    const float* Mm  = (const float*)d_in[4];
    float* out = (float*)d_out;
    char* ws = (char*)d_ws;

    // workspace layout (bytes)
    bf16*  Tb  = (bf16*)(ws + 0);            //  12,582,912  [48 x 8 x 128 x 128]
    bf16*  xT2 = (bf16*)(ws + 12582912);     //   2,097,152  [1024 x 1024]
    bf16*  A2  = (bf16*)(ws + 14680064);     // 106,954,752  [2048 x 26112]
    bf16*  B2  = (bf16*)(ws + 121634816);    //  26,738,688  [ 512 x 26112]
                                             //  total 148,373,504

    prep_all<<<4742, 256, 0, stream>>>(x, phi, M, Mp, Mm, xT2, A2, B2, Tb, out);
    conv_gemm<<<3072, 256, 0, stream>>>(Tb, xT2, A2);
    proj_gemm<<<dim3(8, 2, 16), 512, 0, stream>>>(A2, B2, out);
}

// Round 9
// 256.641 us; speedup vs baseline: 1.0946x; 1.0946x over previous
//
#include <hip/hip_runtime.h>

typedef __bf16 bf16;
typedef bf16 bf16x8 __attribute__((ext_vector_type(8)));
typedef float floatx16 __attribute__((ext_vector_type(16)));

#define AS1 __attribute__((address_space(1)))
#define AS3 __attribute__((address_space(3)))

#define KTOT 26112   // A2/B2 leading dim: 48*512 spectral + 3*512 AR columns

// ---------------------------------------------------------------------------
// Core tile machinery (round-2 verified): 128x128 block, 4 waves (2x2 of
// 64x64), BK=64, 32x32x16 bf16 MFMA. global_load_lds width=16, lane-linear
// LDS, XOR swizzle applied on the GLOBAL column so ds_read_b128 fragment
// loads avoid the 128B-stride bank pathology.
// ---------------------------------------------------------------------------
__device__ __forceinline__ void stage_tile(const bf16* g, int ld, bf16* lds, int tid) {
#pragma unroll
    for (int it = 0; it < 4; ++it) {
        int q    = it * 256 + tid;        // 0..1023, 8 bf16 per q
        int row  = q >> 3;
        int col8 = (q & 7) ^ (row & 7);   // swizzle on global side
        __builtin_amdgcn_global_load_lds(
            (const AS1 void*)(g + (size_t)row * ld + col8 * 8),
            (AS3 void*)(lds + q * 8), 16, 0, 0);
    }
}

// A frag (M=32,K=16): m=lane&31, k=8*(lane>>5)+j. B symmetric. 4 K-steps/BK.
__device__ __forceinline__ void mfma_block(const bf16* lA, const bf16* lB,
                                           floatx16 acc[2][2], int lane, int wm, int wn) {
    const int lrow = lane & 31;
    const int lk   = lane >> 5;
#pragma unroll
    for (int s = 0; s < 4; ++s) {   // four K=16 steps per BK=64
        bf16x8 af[2], bfr[2];
        const int c8 = s * 2 + lk;
#pragma unroll
        for (int mi = 0; mi < 2; ++mi) {
            int r = wm * 64 + mi * 32 + lrow;
            af[mi] = *(const bf16x8*)(lA + r * 64 + ((c8 ^ (r & 7)) << 3));
        }
#pragma unroll
        for (int ni = 0; ni < 2; ++ni) {
            int r = wn * 64 + ni * 32 + lrow;
            bfr[ni] = *(const bf16x8*)(lB + r * 64 + ((c8 ^ (r & 7)) << 3));
        }
#pragma unroll
        for (int mi = 0; mi < 2; ++mi)
#pragma unroll
            for (int ni = 0; ni < 2; ++ni)
                acc[mi][ni] = __builtin_amdgcn_mfma_f32_32x32x16_bf16(
                    af[mi], bfr[ni], acc[mi][ni], 0, 0, 0);
    }
}

// C/D mapping for 32x32 (m74/m101): col=lane&31, row=(r&3)+8*(r>>2)+4*(lane>>5)
#define CD_ROW(r, lane) (((r) & 3) + 8 * ((r) >> 2) + 4 * ((lane) >> 5))

// ---------------------------------------------------------------------------
// Conv phase, even/odd-decomposed (round-2 verified, byte-identical).
// ---------------------------------------------------------------------------
__global__ __launch_bounds__(256) void conv_gemm(const bf16* __restrict__ Tb,
                                                 const bf16* __restrict__ xT2,
                                                 bf16* __restrict__ A2) {
    __shared__ bf16 lA[128 * 64], lB[128 * 64];
    const int tid = threadIdx.x;
    const int lane = tid & 63, wave = tid >> 6, wm = wave & 1, wn = wave >> 1;
    const int bid = blockIdx.x;
    const int a    = 7 - (bid / 384);      // longest-first (LPT)
    const int rem  = bid % 384;
    const int dblk = rem / 48;             // 0..7 over d' = p*512 + d
    const int kw   = rem % 48;             // k*2 + w

    floatx16 acc[2][2];
#pragma unroll
    for (int mi = 0; mi < 2; ++mi)
#pragma unroll
        for (int ni = 0; ni < 2; ++ni)
#pragma unroll
            for (int e = 0; e < 16; ++e) acc[mi][ni][e] = 0.f;

    for (int c = 0; c <= a; ++c) {
        const bf16* Ab = Tb + ((size_t)kw * 8 + (a - c)) * 16384;
        const bf16* Bb = xT2 + (size_t)(dblk * 128) * 1024 + c * 128;
#pragma unroll
        for (int kk = 0; kk < 128; kk += 64) {
            stage_tile(Ab + kk, 128, lA, tid);
            stage_tile(Bb + kk, 1024, lB, tid);
            __syncthreads();
            mfma_block(lA, lB, acc, lane, wm, wn);
            __syncthreads();
        }
    }
    const int w = kw & 1, k = kw >> 1;
    const int kv = w ? (24 + k) : k;
    const int p = dblk >> 2, dbase = (dblk & 3) * 128;
    bf16* Ocol = A2 + (size_t)kv * 512 + dbase;
#pragma unroll
    for (int mi = 0; mi < 2; ++mi)
#pragma unroll
        for (int ni = 0; ni < 2; ++ni)
#pragma unroll
            for (int r = 0; r < 16; ++r) {
                int tau = a * 128 + wm * 64 + mi * 32 + CD_ROW(r, lane);
                int t = 2 * tau + p + w;   // w=0: 2tau+p ; w=1: 2tau+1+p
                if (t < 2048) {
                    int col = wn * 64 + ni * 32 + (lane & 31);
                    Ocol[(size_t)t * KTOT + col] = (bf16)acc[mi][ni][r];
                }
            }
}

// ---------------------------------------------------------------------------
// Projection GEMM (round-2 verified structure): out[t][o] += A2[t][:]*B2[o][:].
// K-split x8 (K=3264 = 51*64) -> grid (16,8,4) = 512 blocks, 2-phase dbuf.
// Epilogue: fp32 atomicAdd into out (zeroed by prep) -- replaces the P2
// partial buffer + reduce8 kernel (numerics verified rounds 4/5/8).
// ---------------------------------------------------------------------------
__global__ __launch_bounds__(256) void proj_gemm(const bf16* __restrict__ A2,
                                                 const bf16* __restrict__ B2,
                                                 float* __restrict__ out) {
    __shared__ bf16 lA[2][128 * 64], lB[2][128 * 64];
    const int tid = threadIdx.x;
    const int lane = tid & 63, wave = tid >> 6, wm = wave & 1, wn = wave >> 1;
    const int bm = blockIdx.x, sp = blockIdx.y, bn = blockIdx.z;
    const bf16* Ab = A2 + (size_t)bm * 128 * KTOT + sp * 3264;
    const bf16* Bb = B2 + (size_t)bn * 128 * KTOT + sp * 3264;

    floatx16 acc[2][2];
#pragma unroll
    for (int mi = 0; mi < 2; ++mi)
#pragma unroll
        for (int ni = 0; ni < 2; ++ni)
#pragma unroll
            for (int e = 0; e < 16; ++e) acc[mi][ni][e] = 0.f;

    stage_tile(Ab, KTOT, lA[0], tid);
    stage_tile(Bb, KTOT, lB[0], tid);
    __syncthreads();
    int cur = 0;
    for (int kk = 0; kk < 3264; kk += 64) {
        if (kk + 64 < 3264) {
            stage_tile(Ab + kk + 64, KTOT, lA[cur ^ 1], tid);
            stage_tile(Bb + kk + 64, KTOT, lB[cur ^ 1], tid);
        }
        mfma_block(lA[cur], lB[cur], acc, lane, wm, wn);
        __syncthreads();   // drains stage vmcnt; ds_reads already lgkm-drained
        cur ^= 1;
    }
#pragma unroll
    for (int mi = 0; mi < 2; ++mi)
#pragma unroll
        for (int ni = 0; ni < 2; ++ni)
#pragma unroll
            for (int r = 0; r < 16; ++r) {
                int t = bm * 128 + wm * 64 + mi * 32 + CD_ROW(r, lane);
                int o = bn * 128 + wn * 64 + ni * 32 + (lane & 31);
                atomicAdd(out + (size_t)t * 512 + o, acc[mi][ni][r]);
            }
}

// ---------------------------------------------------------------------------
// Fused prep (round-2 verified) + out-zeroing (round-8 verified):
//  [0,256)      xT2 parity-split transpose
//  [256,1792)   A2 AR columns (float4 loads)
//  [1792,3328)  B2 spectral: (Mp+Mm) -> kv=k, (Mp-Mm) -> kv=24+k, one pass
//  [3328,3840)  B2 AR columns
//  [3840,4224)  Tb E/O Toeplitz kernels
//  [4224,4230)  zero A2 row t=0, K-cols [12288,24576)
//  [4230,4742)  zero out (2048x512 f32) for proj's atomics
// ---------------------------------------------------------------------------
__global__ void prep_all(const float* __restrict__ x, const float* __restrict__ phi,
                         const float* __restrict__ M, const float* __restrict__ Mp,
                         const float* __restrict__ Mm, bf16* __restrict__ xT2,
                         bf16* __restrict__ A2, bf16* __restrict__ B2,
                         bf16* __restrict__ Tb, float* __restrict__ out) {
    __shared__ float smem[2][64 * 65];
    const int b = blockIdx.x, tid = threadIdx.x;
    if (b < 256) {
        // xT2: 64x64 LDS transpose tiles over (sigma, d')
        int dpt = (b >> 4) * 64, st = (b & 15) * 64;
        int p = dpt >> 9, dbase = dpt & 511;
#pragma unroll
        for (int it = 0; it < 16; ++it) {
            int q = it * 256 + tid;
            int r = q >> 6, cc = q & 63;   // r = sigma-local, cc = d-local
            smem[0][r * 65 + cc] = x[(size_t)(2 * (st + r) + p) * 512 + dbase + cc];
        }
        __syncthreads();
#pragma unroll
        for (int it = 0; it < 2; ++it) {
            int q = it * 256 + tid;
            int r = q >> 3, c8 = q & 7;    // r = d'-local, c8 = sigma-local/8
            bf16x8 v;
#pragma unroll
            for (int jj = 0; jj < 8; ++jj)
                v[jj] = (bf16)smem[0][(c8 * 8 + jj) * 65 + r];
            *(bf16x8*)&xT2[(size_t)(dpt + r) * 1024 + st + c8 * 8] = v;
        }
    } else if (b < 1792) {
        // A2 AR columns: A2[t][24576 + i*512 + d] = x[t-i][d]
        int idx8 = (b - 256) * 256 + tid;   // over 2048*192
        int t = idx8 / 192, q = idx8 % 192;
        int i = q >> 6, d8 = (q & 63) * 8;
        bf16x8 v;
        if (t - i >= 0) {
            const float* xp = x + (size_t)(t - i) * 512 + d8;
            float4 f0 = *(const float4*)(xp);
            float4 f1 = *(const float4*)(xp + 4);
            v[0] = (bf16)f0.x; v[1] = (bf16)f0.y; v[2] = (bf16)f0.z; v[3] = (bf16)f0.w;
            v[4] = (bf16)f1.x; v[5] = (bf16)f1.y; v[6] = (bf16)f1.z; v[7] = (bf16)f1.w;
        } else {
#pragma unroll
            for (int jj = 0; jj < 8; ++jj) v[jj] = (bf16)0.f;
        }
        *(bf16x8*)(A2 + (size_t)t * KTOT + 24576 + i * 512 + d8) = v;
    } else if (b < 3328) {
        // B2[o][k*512+d] = (Mp+Mm)[k][d][o];  B2[o][(24+k)*512+d] = (Mp-Mm)[k][d][o]
        int b2 = b - 1792;
        int k = b2 >> 6, rem2 = b2 & 63;
        int dt = (rem2 >> 3) * 64, ot = (rem2 & 7) * 64;
        const float* Sp = Mp + (size_t)k * 262144;
        const float* Sm = Mm + (size_t)k * 262144;
#pragma unroll
        for (int it = 0; it < 16; ++it) {
            int q = it * 256 + tid;
            int r = q >> 6, cc = q & 63;   // r = d-local, cc = o-local
            smem[0][r * 65 + cc] = Sp[(size_t)(dt + r) * 512 + ot + cc];
            smem[1][r * 65 + cc] = Sm[(size_t)(dt + r) * 512 + ot + cc];
        }
        __syncthreads();
#pragma unroll
        for (int it = 0; it < 2; ++it) {
            int q = it * 256 + tid;
            int r = q >> 3, c8 = q & 7;    // r = o-local, c8 = d-local/8
            bf16x8 vs, vd;
#pragma unroll
            for (int jj = 0; jj < 8; ++jj) {
                float av = smem[0][(c8 * 8 + jj) * 65 + r];
                float bv = smem[1][(c8 * 8 + jj) * 65 + r];
                vs[jj] = (bf16)(av + bv);
                vd[jj] = (bf16)(av - bv);
            }
            *(bf16x8*)&B2[(size_t)(ot + r) * KTOT + k * 512 + dt + c8 * 8] = vs;
            *(bf16x8*)&B2[(size_t)(ot + r) * KTOT + (24 + k) * 512 + dt + c8 * 8] = vd;
        }
    } else if (b < 3840) {
        // B2 AR columns: B2[o][24576 + i*512 + d] = M[o][d][i]
        int o = b - 3328;
        for (int q = tid; q < 1536; q += 256) smem[0][q] = M[(size_t)o * 1536 + q];
        __syncthreads();
        if (tid < 192) {
            int q = tid * 8;
            int i = q >> 9, d0 = q & 511;
            bf16x8 v;
#pragma unroll
            for (int jj = 0; jj < 8; ++jj) v[jj] = (bf16)smem[0][(d0 + jj) * 3 + i];
            *(bf16x8*)&B2[(size_t)o * KTOT + 24576 + q] = v;
        }
    } else if (b < 4224) {
        // Tb fill, one block per (kw,m): kernel phi_even (w=0) or phi_odd (w=1)
        int b3 = b - 3840;              // 0..383
        int kw = b3 >> 3, m = b3 & 7;
        int k = kw >> 1, w = kw & 1;
        if (tid < 255) {
            int sh = m * 128 - 127 + tid;
            smem[0][tid] = (sh >= 0) ? phi[(size_t)(2 * sh + w) * 24 + k] : 0.f;
        }
        __syncthreads();
        bf16* Tp = Tb + (size_t)b3 * 16384;
#pragma unroll
        for (int it = 0; it < 8; ++it) {
            int q = it * 256 + tid;     // over 128 i x 16 j8
            int i = q >> 4, j8 = (q & 15) * 8;
            bf16x8 v;
#pragma unroll
            for (int jj = 0; jj < 8; ++jj)
                v[jj] = (bf16)smem[0][127 + i - (j8 + jj)];
            *(bf16x8*)(Tp + i * 128 + j8) = v;
        }
    } else if (b < 4230) {
        // zero A2[0][12288..24576): O-part has no contribution at t=0
        int off = 12288 + (b - 4224) * 2048 + tid * 8;
        bf16x8 z;
#pragma unroll
        for (int jj = 0; jj < 8; ++jj) z[jj] = (bf16)0.f;
        *(bf16x8*)(A2 + off) = z;
    } else {
        // zero out: 2048*512 f32
        int idx = ((b - 4230) * 256 + tid) * 8;
        float4 z4 = make_float4(0.f, 0.f, 0.f, 0.f);
        *(float4*)(out + idx)     = z4;
        *(float4*)(out + idx + 4) = z4;
    }
}

// ---------------------------------------------------------------------------
// Launch
// ---------------------------------------------------------------------------
extern "C" void kernel_launch(void* const* d_in, const int* in_sizes, int n_in,
                              void* d_out, int out_size, void* d_ws, size_t ws_size,
                              hipStream_t stream) {
    const float* x   = (const float*)d_in[0];
    const float* phi = (const float*)d_in[1];
    const float* M   = (const float*)d_in[2];
    const float* Mp  = (const float*)d_in[3];
    const float* Mm  = (const float*)d_in[4];
    float* out = (float*)d_out;
    char* ws = (char*)d_ws;

    // workspace layout (bytes)
    bf16*  Tb  = (bf16*)(ws + 0);            //  12,582,912  [48 x 8 x 128 x 128]
    bf16*  xT2 = (bf16*)(ws + 12582912);     //   2,097,152  [1024 x 1024]
    bf16*  A2  = (bf16*)(ws + 14680064);     // 106,954,752  [2048 x 26112]
    bf16*  B2  = (bf16*)(ws + 121634816);    //  26,738,688  [ 512 x 26112]
                                             //  total 148,373,504

    prep_all<<<4742, 256, 0, stream>>>(x, phi, M, Mp, Mm, xT2, A2, B2, Tb, out);
    conv_gemm<<<3072, 256, 0, stream>>>(Tb, xT2, A2);
    proj_gemm<<<dim3(16, 8, 4), 256, 0, stream>>>(A2, B2, out);
}

// Round 10
// 249.605 us; speedup vs baseline: 1.1254x; 1.0282x over previous
//
#include <hip/hip_runtime.h>

typedef __bf16 bf16;
typedef bf16 bf16x8 __attribute__((ext_vector_type(8)));
typedef float floatx16 __attribute__((ext_vector_type(16)));

#define AS1 __attribute__((address_space(1)))
#define AS3 __attribute__((address_space(3)))

#define KTOT 26112   // A2/B2 leading dim: 48*512 spectral + 3*512 AR columns

// ---------------------------------------------------------------------------
// Core tile machinery (round-2 verified).
// ---------------------------------------------------------------------------
__device__ __forceinline__ void stage_tile(const bf16* g, int ld, bf16* lds, int tid) {
#pragma unroll
    for (int it = 0; it < 4; ++it) {
        int q    = it * 256 + tid;        // 0..1023, 8 bf16 per q
        int row  = q >> 3;
        int col8 = (q & 7) ^ (row & 7);   // swizzle on global side
        __builtin_amdgcn_global_load_lds(
            (const AS1 void*)(g + (size_t)row * ld + col8 * 8),
            (AS3 void*)(lds + q * 8), 16, 0, 0);
    }
}

__device__ __forceinline__ void mfma_block(const bf16* lA, const bf16* lB,
                                           floatx16 acc[2][2], int lane, int wm, int wn) {
    const int lrow = lane & 31;
    const int lk   = lane >> 5;
#pragma unroll
    for (int s = 0; s < 4; ++s) {   // four K=16 steps per BK=64
        bf16x8 af[2], bfr[2];
        const int c8 = s * 2 + lk;
#pragma unroll
        for (int mi = 0; mi < 2; ++mi) {
            int r = wm * 64 + mi * 32 + lrow;
            af[mi] = *(const bf16x8*)(lA + r * 64 + ((c8 ^ (r & 7)) << 3));
        }
#pragma unroll
        for (int ni = 0; ni < 2; ++ni) {
            int r = wn * 64 + ni * 32 + lrow;
            bfr[ni] = *(const bf16x8*)(lB + r * 64 + ((c8 ^ (r & 7)) << 3));
        }
#pragma unroll
        for (int mi = 0; mi < 2; ++mi)
#pragma unroll
            for (int ni = 0; ni < 2; ++ni)
                acc[mi][ni] = __builtin_amdgcn_mfma_f32_32x32x16_bf16(
                    af[mi], bfr[ni], acc[mi][ni], 0, 0, 0);
    }
}

// C/D mapping for 32x32 (m74/m101): col=lane&31, row=(r&3)+8*(r>>2)+4*(lane>>5)
#define CD_ROW(r, lane) (((r) & 3) + 8 * ((r) >> 2) + 4 * ((lane) >> 5))

// ---------------------------------------------------------------------------
// prep_io: conv's true input dependencies only (round-6 verified).
//  [0,256)   xT2[p*512+d][sig] = x[2sig+p][d]  (parity-split transpose)
//  [256,640) Tb[kw][m][i][j] = phi[2*(m*128+i-j)+w][k]  (E/O Toeplitz kernels)
// ---------------------------------------------------------------------------
__global__ void prep_io(const float* __restrict__ x, const float* __restrict__ phi,
                        bf16* __restrict__ xT2, bf16* __restrict__ Tb) {
    __shared__ float smem[64 * 65];
    const int b = blockIdx.x, tid = threadIdx.x;
    if (b < 256) {
        int dpt = (b >> 4) * 64, st = (b & 15) * 64;
        int p = dpt >> 9, dbase = dpt & 511;
#pragma unroll
        for (int it = 0; it < 16; ++it) {
            int q = it * 256 + tid;
            int r = q >> 6, cc = q & 63;   // r = sigma-local, cc = d-local
            smem[r * 65 + cc] = x[(size_t)(2 * (st + r) + p) * 512 + dbase + cc];
        }
        __syncthreads();
#pragma unroll
        for (int it = 0; it < 2; ++it) {
            int q = it * 256 + tid;
            int r = q >> 3, c8 = q & 7;    // r = d'-local, c8 = sigma-local/8
            bf16x8 v;
#pragma unroll
            for (int jj = 0; jj < 8; ++jj)
                v[jj] = (bf16)smem[(c8 * 8 + jj) * 65 + r];
            *(bf16x8*)&xT2[(size_t)(dpt + r) * 1024 + st + c8 * 8] = v;
        }
    } else {
        int b3 = b - 256;               // 0..383: (kw, m)
        int kw = b3 >> 3, m = b3 & 7;
        int k = kw >> 1, w = kw & 1;
        if (tid < 255) {
            int sh = m * 128 - 127 + tid;
            smem[tid] = (sh >= 0) ? phi[(size_t)(2 * sh + w) * 24 + k] : 0.f;
        }
        __syncthreads();
        bf16* Tp = Tb + (size_t)b3 * 16384;
#pragma unroll
        for (int it = 0; it < 8; ++it) {
            int q = it * 256 + tid;     // over 128 i x 16 j8
            int i = q >> 4, j8 = (q & 15) * 8;
            bf16x8 v;
#pragma unroll
            for (int jj = 0; jj < 8; ++jj)
                v[jj] = (bf16)smem[127 + i - (j8 + jj)];
            *(bf16x8*)(Tp + i * 128 + j8) = v;
        }
    }
}

// ---------------------------------------------------------------------------
// conv_fused: prep-rest blocks FIRST (bid < 3590), conv blocks after
// (bid >= 3590). Round-6 verified the merged code paths (correctness +
// address-disjointness); this round only swaps the dispatch order so the
// short memory-bound prep blocks fill CUs during conv's ramp instead of
// running as a serial tail. Address disjointness: prep-rest writes A2 AR
// cols [24576,26112) + A2 row-0 cols [12288,24576) (never written by conv's
// w=1 blocks, whose min row is 1) + all of B2; conv writes A2 spectral
// cols [0,24576) rows per (w,p).
// ---------------------------------------------------------------------------
__global__ __launch_bounds__(256) void conv_fused(const bf16* __restrict__ Tb,
                                                  const bf16* __restrict__ xT2,
                                                  bf16* __restrict__ A2,
                                                  const float* __restrict__ x,
                                                  const float* __restrict__ M,
                                                  const float* __restrict__ Mp,
                                                  const float* __restrict__ Mm,
                                                  bf16* __restrict__ B2) {
    __shared__ float smemf[2][64 * 65];   // 33.3 KB union (conv aliases 32 KB)
    const int tid = threadIdx.x;
    const int bid = blockIdx.x;

    if (bid >= 3590) {
        // ---- conv (round-2 verified, byte-identical math) ----
        bf16* lA = (bf16*)smemf;            // 16 KB
        bf16* lB = lA + 128 * 64;           // 16 KB
        const int bid2 = bid - 3590;
        const int lane = tid & 63, wave = tid >> 6, wm = wave & 1, wn = wave >> 1;
        const int a    = 7 - (bid2 / 384);  // longest-first (LPT)
        const int rem  = bid2 % 384;
        const int dblk = rem / 48;          // 0..7 over d' = p*512 + d
        const int kw   = rem % 48;          // k*2 + w

        floatx16 acc[2][2];
#pragma unroll
        for (int mi = 0; mi < 2; ++mi)
#pragma unroll
            for (int ni = 0; ni < 2; ++ni)
#pragma unroll
                for (int e = 0; e < 16; ++e) acc[mi][ni][e] = 0.f;

        for (int c = 0; c <= a; ++c) {
            const bf16* Ab = Tb + ((size_t)kw * 8 + (a - c)) * 16384;
            const bf16* Bb = xT2 + (size_t)(dblk * 128) * 1024 + c * 128;
#pragma unroll
            for (int kk = 0; kk < 128; kk += 64) {
                stage_tile(Ab + kk, 128, lA, tid);
                stage_tile(Bb + kk, 1024, lB, tid);
                __syncthreads();
                mfma_block(lA, lB, acc, lane, wm, wn);
                __syncthreads();
            }
        }
        const int w = kw & 1, k = kw >> 1;
        const int kv = w ? (24 + k) : k;
        const int p = dblk >> 2, dbase = (dblk & 3) * 128;
        bf16* Ocol = A2 + (size_t)kv * 512 + dbase;
#pragma unroll
        for (int mi = 0; mi < 2; ++mi)
#pragma unroll
            for (int ni = 0; ni < 2; ++ni)
#pragma unroll
                for (int r = 0; r < 16; ++r) {
                    int tau = a * 128 + wm * 64 + mi * 32 + CD_ROW(r, lane);
                    int t = 2 * tau + p + w;   // w=0: 2tau+p ; w=1: 2tau+1+p
                    if (t < 2048) {
                        int col = wn * 64 + ni * 32 + (lane & 31);
                        Ocol[(size_t)t * KTOT + col] = (bf16)acc[mi][ni][r];
                    }
                }
        return;
    }

    // ---- prep-rest (round-6 verified paths) ----
    const int b = bid;
    if (b < 1536) {
        // A2 AR columns: A2[t][24576 + i*512 + d] = x[t-i][d]
        int idx8 = b * 256 + tid;           // over 2048*192
        int t = idx8 / 192, q = idx8 % 192;
        int i = q >> 6, d8 = (q & 63) * 8;
        bf16x8 v;
        if (t - i >= 0) {
            const float* xp = x + (size_t)(t - i) * 512 + d8;
            float4 f0 = *(const float4*)(xp);
            float4 f1 = *(const float4*)(xp + 4);
            v[0] = (bf16)f0.x; v[1] = (bf16)f0.y; v[2] = (bf16)f0.z; v[3] = (bf16)f0.w;
            v[4] = (bf16)f1.x; v[5] = (bf16)f1.y; v[6] = (bf16)f1.z; v[7] = (bf16)f1.w;
        } else {
#pragma unroll
            for (int jj = 0; jj < 8; ++jj) v[jj] = (bf16)0.f;
        }
        *(bf16x8*)(A2 + (size_t)t * KTOT + 24576 + i * 512 + d8) = v;
    } else if (b < 3072) {
        // B2[o][k*512+d] = (Mp+Mm)[k][d][o];  B2[o][(24+k)*512+d] = (Mp-Mm)[k][d][o]
        int b2 = b - 1536;
        int k = b2 >> 6, rem2 = b2 & 63;
        int dt = (rem2 >> 3) * 64, ot = (rem2 & 7) * 64;
        const float* Sp = Mp + (size_t)k * 262144;
        const float* Sm = Mm + (size_t)k * 262144;
#pragma unroll
        for (int it = 0; it < 16; ++it) {
            int q = it * 256 + tid;
            int r = q >> 6, cc = q & 63;   // r = d-local, cc = o-local
            smemf[0][r * 65 + cc] = Sp[(size_t)(dt + r) * 512 + ot + cc];
            smemf[1][r * 65 + cc] = Sm[(size_t)(dt + r) * 512 + ot + cc];
        }
        __syncthreads();
#pragma unroll
        for (int it = 0; it < 2; ++it) {
            int q = it * 256 + tid;
            int r = q >> 3, c8 = q & 7;    // r = o-local, c8 = d-local/8
            bf16x8 vs, vd;
#pragma unroll
            for (int jj = 0; jj < 8; ++jj) {
                float av = smemf[0][(c8 * 8 + jj) * 65 + r];
                float bv = smemf[1][(c8 * 8 + jj) * 65 + r];
                vs[jj] = (bf16)(av + bv);
                vd[jj] = (bf16)(av - bv);
            }
            *(bf16x8*)&B2[(size_t)(ot + r) * KTOT + k * 512 + dt + c8 * 8] = vs;
            *(bf16x8*)&B2[(size_t)(ot + r) * KTOT + (24 + k) * 512 + dt + c8 * 8] = vd;
        }
    } else if (b < 3584) {
        // B2 AR columns: B2[o][24576 + i*512 + d] = M[o][d][i]
        int o = b - 3072;
        float* sm = smemf[0];
        for (int q = tid; q < 1536; q += 256) sm[q] = M[(size_t)o * 1536 + q];
        __syncthreads();
        if (tid < 192) {
            int q = tid * 8;
            int i = q >> 9, d0 = q & 511;
            bf16x8 v;
#pragma unroll
            for (int jj = 0; jj < 8; ++jj) v[jj] = (bf16)sm[(d0 + jj) * 3 + i];
            *(bf16x8*)&B2[(size_t)o * KTOT + 24576 + q] = v;
        }
    } else {
        // zero A2[0][12288..24576): odd part has no contribution at t=0
        int off = 12288 + (b - 3584) * 2048 + tid * 8;
        bf16x8 z;
#pragma unroll
        for (int jj = 0; jj < 8; ++jj) z[jj] = (bf16)0.f;
        *(bf16x8*)(A2 + off) = z;
    }
}

// ---------------------------------------------------------------------------
// Projection GEMM (round-2 verified): out[t][o] = sum_K A2[t][K] * B2[o][K].
// K-split x8 (K=3264 = 51*64) -> grid (16,8,4) = 512 blocks, 2-phase dbuf.
// ---------------------------------------------------------------------------
__global__ __launch_bounds__(256) void proj_gemm(const bf16* __restrict__ A2,
                                                 const bf16* __restrict__ B2,
                                                 float* __restrict__ P2) {
    __shared__ bf16 lA[2][128 * 64], lB[2][128 * 64];
    const int tid = threadIdx.x;
    const int lane = tid & 63, wave = tid >> 6, wm = wave & 1, wn = wave >> 1;
    const int bm = blockIdx.x, sp = blockIdx.y, bn = blockIdx.z;
    const bf16* Ab = A2 + (size_t)bm * 128 * KTOT + sp * 3264;
    const bf16* Bb = B2 + (size_t)bn * 128 * KTOT + sp * 3264;

    floatx16 acc[2][2];
#pragma unroll
    for (int mi = 0; mi < 2; ++mi)
#pragma unroll
        for (int ni = 0; ni < 2; ++ni)
#pragma unroll
            for (int e = 0; e < 16; ++e) acc[mi][ni][e] = 0.f;

    stage_tile(Ab, KTOT, lA[0], tid);
    stage_tile(Bb, KTOT, lB[0], tid);
    __syncthreads();
    int cur = 0;
    for (int kk = 0; kk < 3264; kk += 64) {
        if (kk + 64 < 3264) {
            stage_tile(Ab + kk + 64, KTOT, lA[cur ^ 1], tid);
            stage_tile(Bb + kk + 64, KTOT, lB[cur ^ 1], tid);
        }
        mfma_block(lA[cur], lB[cur], acc, lane, wm, wn);
        __syncthreads();   // drains stage vmcnt; ds_reads already lgkm-drained
        cur ^= 1;
    }
    float* Pt = P2 + (size_t)sp * 1048576;
#pragma unroll
    for (int mi = 0; mi < 2; ++mi)
#pragma unroll
        for (int ni = 0; ni < 2; ++ni)
#pragma unroll
            for (int r = 0; r < 16; ++r) {
                int t = bm * 128 + wm * 64 + mi * 32 + CD_ROW(r, lane);
                int o = bn * 128 + wn * 64 + ni * 32 + (lane & 31);
                Pt[(size_t)t * 512 + o] = acc[mi][ni][r];
            }
}

// ---------------------------------------------------------------------------
// reduce: out = sum of 8 K-split partials (round-2 verified)
// ---------------------------------------------------------------------------
__global__ void reduce8(const float* __restrict__ P2, float* __restrict__ out) {
    int idx = blockIdx.x * 256 + threadIdx.x;   // over 2048*512
    if (idx >= 2048 * 512) return;
    float s = 0.f;
#pragma unroll
    for (int sp = 0; sp < 8; ++sp)
        s += P2[(size_t)sp * 1048576 + idx];
    out[idx] = s;
}

// ---------------------------------------------------------------------------
// Launch
// ---------------------------------------------------------------------------
extern "C" void kernel_launch(void* const* d_in, const int* in_sizes, int n_in,
                              void* d_out, int out_size, void* d_ws, size_t ws_size,
                              hipStream_t stream) {
    const float* x   = (const float*)d_in[0];
    const float* phi = (const float*)d_in[1];
    const float* M   = (const float*)d_in[2];
    const float* Mp  = (const float*)d_in[3];
    const float* Mm  = (const float*)d_in[4];
    float* out = (float*)d_out;
    char* ws = (char*)d_ws;

    // workspace layout (bytes)
    bf16*  Tb  = (bf16*)(ws + 0);            //  12,582,912  [48 x 8 x 128 x 128]
    bf16*  xT2 = (bf16*)(ws + 12582912);     //   2,097,152  [1024 x 1024]
    bf16*  A2  = (bf16*)(ws + 14680064);     // 106,954,752  [2048 x 26112]
    bf16*  B2  = (bf16*)(ws + 121634816);    //  26,738,688  [ 512 x 26112]
    float* P2  = (float*)(ws + 148373504);   //  33,554,432  [ 8 x 2048 x 512]
                                             //  total 181,927,936

    prep_io<<<640, 256, 0, stream>>>(x, phi, xT2, Tb);
    conv_fused<<<6662, 256, 0, stream>>>(Tb, xT2, A2, x, M, Mp, Mm, B2);
    proj_gemm<<<dim3(16, 8, 4), 256, 0, stream>>>(A2, B2, P2);
    reduce8<<<4096, 256, 0, stream>>>(P2, out);
}